// Round 1
// baseline (324.056 us; speedup 1.0000x reference)
//
#include <hip/hip_runtime.h>

#define BB 256
#define TT 1024
#define LL 50
#define START_I 47
#define END_I 48

__device__ __forceinline__ float rdlane(float v, int i) {
  return __int_as_float(__builtin_amdgcn_readlane(__float_as_int(v), i));
}

// One wave per sequence. Forward recurrence in scaled-linear domain:
//   q[j] = exp(alpha[j] - 64*ln2*cnt),  q_new[j] = (sum_i q[i]*E[i][j]) * exp(emit[j])
// E[i][j] = exp(trans[i][j]) precomputed in registers (column j in lane j).
__global__ __launch_bounds__(64) void crf_fwd(
    const float* __restrict__ lstm, const float* __restrict__ trans,
    const int* __restrict__ lens, const int* __restrict__ tags,
    float* __restrict__ ws) {
  const int b = blockIdx.x;
  const int lane = threadIdx.x;
  const bool act = lane < LL;
  const int len = lens[b];

  // ---- load E column (lane j holds E[0..49][j]) ----
  float e[LL];
#pragma unroll
  for (int i = 0; i < LL; ++i) {
    float ev = 0.0f;
    if (act) ev = __expf(trans[i * LL + lane]);
    e[i] = ev;
  }

  // ---- alpha0 -> q ----
  const float* emrow = lstm + (size_t)b * TT * LL + lane;  // + t*LL per step
  float q = 0.0f;
  if (act) q = __expf(trans[START_I * LL + lane] + emrow[0]);
  int cnt = 0;  // number of 2^64 down-scales; alpha = 64*ln2*cnt + ln(q)

  // ---- emit prefetch ring (8 deep) ----
  float ebuf[8];
#pragma unroll
  for (int k = 0; k < 8; ++k) {
    int t = 1 + k;
    ebuf[k] = (act && t < len) ? emrow[(size_t)t * LL] : 0.0f;
  }

  // ---- main sequential loop over t ----
  for (int tb = 1; tb < len; tb += 8) {
#pragma unroll
    for (int u = 0; u < 8; ++u) {
      int t = tb + u;
      if (t >= len) break;  // wave-uniform
      float acc0 = 0.f, acc1 = 0.f, acc2 = 0.f, acc3 = 0.f;
#pragma unroll
      for (int i = 0; i < 48; i += 4) {
        acc0 = fmaf(rdlane(q, i + 0), e[i + 0], acc0);
        acc1 = fmaf(rdlane(q, i + 1), e[i + 1], acc1);
        acc2 = fmaf(rdlane(q, i + 2), e[i + 2], acc2);
        acc3 = fmaf(rdlane(q, i + 3), e[i + 3], acc3);
      }
      acc0 = fmaf(rdlane(q, 48), e[48], acc0);
      acc1 = fmaf(rdlane(q, 49), e[49], acc1);
      float f = __expf(ebuf[u]);
      float qn = ((acc0 + acc1) + (acc2 + acc3)) * f;
      // refill prefetch slot (used 8 iterations from now)
      int tn = t + 8;
      ebuf[u] = (act && tn < len) ? emrow[(size_t)tn * LL] : 0.0f;
      // lazy rescale (wave-uniform branch, ~every 11 steps)
      if (__any(qn >= 0x1p64f)) { qn *= 0x1p-64f; cnt++; }
      else if (!__any(qn >= 0x1p-64f)) { qn *= 0x1p64f; cnt--; }
      q = qn;
    }
  }

  // ---- unlabeled_b = 64*ln2*cnt + ln( sum_j q[j]*exp(trans[j][END]) ) ----
  float w = 0.0f;
  if (act) w = q * __expf(trans[lane * LL + END_I]);
#pragma unroll
  for (int off = 32; off > 0; off >>= 1) w += __shfl_xor(w, off, 64);
  float unl = (float)cnt * 44.361419555836498f + __logf(w);

  // ---- labeled path (fused; gathers over t in lane-strides of 64) ----
  const int* tg = tags + (size_t)b * TT;
  float lab = 0.0f;
  for (int t0 = 0; t0 < len; t0 += 64) {
    int t = t0 + lane;
    if (t >= 1 && t < len) {
      int tp = tg[t - 1];
      int tc = tg[t];
      lab += trans[tp * LL + tc] + lstm[((size_t)b * TT + t) * LL + tc];
    }
  }
#pragma unroll
  for (int off = 32; off > 0; off >>= 1) lab += __shfl_xor(lab, off, 64);

  if (lane == 0) {
    int tg0 = tg[0];
    float begin = trans[START_I * LL + tg0] + lstm[(size_t)b * TT * LL + tg0];
    int tgl = tg[len - 1];
    float endv = trans[tgl * LL + END_I];
    ws[b] = unl;
    ws[BB + b] = lab + begin + endv;
  }
}

// Deterministic final reduce: ws[0..255] -> out[0], ws[256..511] -> out[1]
__global__ __launch_bounds__(256) void crf_reduce(const float* __restrict__ ws,
                                                  float* __restrict__ out) {
  __shared__ float sm[8];
  int tid = threadIdx.x;
  float u = ws[tid];
  float l = ws[BB + tid];
#pragma unroll
  for (int off = 32; off > 0; off >>= 1) {
    u += __shfl_xor(u, off, 64);
    l += __shfl_xor(l, off, 64);
  }
  int wid = tid >> 6;
  if ((tid & 63) == 0) { sm[wid] = u; sm[4 + wid] = l; }
  __syncthreads();
  if (tid == 0) {
    out[0] = (sm[0] + sm[1]) + (sm[2] + sm[3]);
    out[1] = (sm[4] + sm[5]) + (sm[6] + sm[7]);
  }
}

extern "C" void kernel_launch(void* const* d_in, const int* in_sizes, int n_in,
                              void* d_out, int out_size, void* d_ws, size_t ws_size,
                              hipStream_t stream) {
  const float* lstm = (const float*)d_in[0];
  const float* trans = (const float*)d_in[1];
  const int* lens = (const int*)d_in[2];
  const int* tags = (const int*)d_in[3];
  // d_in[4] (mask) is redundant: mask[b,t] = t < lens[b]
  float* ws = (float*)d_ws;
  float* out = (float*)d_out;

  crf_fwd<<<dim3(BB), dim3(64), 0, stream>>>(lstm, trans, lens, tags, ws);
  crf_reduce<<<dim3(1), dim3(256), 0, stream>>>(ws, out);
}

// Round 2
// 256.349 us; speedup vs baseline: 1.2641x; 1.2641x over previous
//
#include <hip/hip_runtime.h>

#define BB 256
#define TT 1024
#define LL 50
#define START_I 47
#define END_I 48

__device__ __forceinline__ float rdlane(float v, int i) {
  return __int_as_float(__builtin_amdgcn_readlane(__float_as_int(v), i));
}

// One wave per sequence. Forward recurrence in scaled-linear domain:
//   q[j] = exp(alpha[j] - 64*ln2*cnt),  q_new[j] = (sum_i q[i]*E[i][j]) * exp(emit[j])
// E[i][j] = exp(trans[i][j]) held in 50 VGPRs (column j in lane j).
__global__ __launch_bounds__(64, 1) void crf_fwd(
    const float* __restrict__ lstm, const float* __restrict__ trans,
    const int* __restrict__ lens, const int* __restrict__ tags,
    float* __restrict__ ws) {
  const int b = blockIdx.x;
  const int lane = threadIdx.x;
  const bool act = lane < LL;
  const int len = lens[b];

  // ---- load E column (lane j holds E[0..49][j]); 0 for dead lanes ----
  float e[LL];
#pragma unroll
  for (int i = 0; i < LL; ++i) {
    float ev = 0.0f;
    if (act) ev = __expf(trans[i * LL + lane]);
    e[i] = ev;
  }

  // Per-lane emit pointer; dead lanes clamp to column 49 (harmless reads).
  const int col = act ? lane : (LL - 1);
  const float* __restrict__ base = lstm + (size_t)b * TT * LL + col;

  // ---- alpha0 -> q (dead lanes: q = 0) ----
  float q = act ? __expf(trans[START_I * LL + lane] + base[0]) : 0.0f;
  int cnt = 0;  // alpha = 64*ln2*cnt + ln(q)

  // ---- one recurrence step ----
  auto STEP = [&](float em) {
    float acc0 = 0.f, acc1 = 0.f, acc2 = 0.f, acc3 = 0.f;
#pragma unroll
    for (int i = 0; i < 48; i += 4) {
      acc0 = fmaf(rdlane(q, i + 0), e[i + 0], acc0);
      acc1 = fmaf(rdlane(q, i + 1), e[i + 1], acc1);
      acc2 = fmaf(rdlane(q, i + 2), e[i + 2], acc2);
      acc3 = fmaf(rdlane(q, i + 3), e[i + 3], acc3);
    }
    acc0 = fmaf(rdlane(q, 48), e[48], acc0);
    acc1 = fmaf(rdlane(q, 49), e[49], acc1);
    float qn = ((acc0 + acc1) + (acc2 + acc3)) * __expf(em);
    // lazy wave-uniform rescale (~every 10+ steps); NaN in dead lanes is inert
    if (__any(qn >= 0x1p64f)) { qn *= 0x1p-64f; cnt++; }
    else if (!__any(qn >= 0x1p-64f)) { qn *= 0x1p64f; cnt--; }
    q = qn;
  };

  // ---- prefetch ring, 8 deep, constant-immediate-offset loads ----
  float ebuf[8];
  const float* p = base + LL;  // t = 1
#pragma unroll
  for (int k = 0; k < 8; ++k) ebuf[k] = p[k * LL];  // t=1..8, always in-row

  const int nb = (len - 1) >> 3;
  const int rem = (len - 1) & 7;

  for (int blk = 0; blk < nb; ++blk) {
    const float* pf = p + 8 * LL;  // refill source: t = 9 + 8*blk + u
    if (blk < 126) {               // 9+8*125+7 = 1016+7 = 1023 <= TT-1: always safe
#pragma unroll
      for (int u = 0; u < 8; ++u) {
        STEP(ebuf[u]);
        ebuf[u] = pf[u * LL];
      }
    } else {                       // last <=2 blocks: guard row overrun
#pragma unroll
      for (int u = 0; u < 8; ++u) {
        STEP(ebuf[u]);
        int tn = 9 + 8 * blk + u;
        if (tn < TT) ebuf[u] = pf[u * LL];
      }
    }
    p = pf;
  }
  for (int u = 0; u < rem; ++u) STEP(ebuf[u]);

  // ---- unlabeled_b = 64*ln2*cnt + ln( sum_j q[j]*exp(trans[j][END]) ) ----
  float w = 0.0f;
  if (act) w = q * __expf(trans[lane * LL + END_I]);
#pragma unroll
  for (int off = 32; off > 0; off >>= 1) w += __shfl_xor(w, off, 64);
  float unl = (float)cnt * 44.361419555836498f + __logf(w);

  // ---- labeled path (gathers over t in lane-strides of 64) ----
  const int* tg = tags + (size_t)b * TT;
  float lab = 0.0f;
  for (int t0 = 0; t0 < len; t0 += 64) {
    int t = t0 + lane;
    if (t >= 1 && t < len) {
      int tp = tg[t - 1];
      int tc = tg[t];
      lab += trans[tp * LL + tc] + lstm[((size_t)b * TT + t) * LL + tc];
    }
  }
#pragma unroll
  for (int off = 32; off > 0; off >>= 1) lab += __shfl_xor(lab, off, 64);

  if (lane == 0) {
    int tg0 = tg[0];
    float begin = trans[START_I * LL + tg0] + lstm[(size_t)b * TT * LL + tg0];
    int tgl = tg[len - 1];
    float endv = trans[tgl * LL + END_I];
    ws[b] = unl;
    ws[BB + b] = lab + begin + endv;
  }
}

// Deterministic final reduce: ws[0..255] -> out[0], ws[256..511] -> out[1]
__global__ __launch_bounds__(256) void crf_reduce(const float* __restrict__ ws,
                                                  float* __restrict__ out) {
  __shared__ float sm[8];
  int tid = threadIdx.x;
  float u = ws[tid];
  float l = ws[BB + tid];
#pragma unroll
  for (int off = 32; off > 0; off >>= 1) {
    u += __shfl_xor(u, off, 64);
    l += __shfl_xor(l, off, 64);
  }
  int wid = tid >> 6;
  if ((tid & 63) == 0) { sm[wid] = u; sm[4 + wid] = l; }
  __syncthreads();
  if (tid == 0) {
    out[0] = (sm[0] + sm[1]) + (sm[2] + sm[3]);
    out[1] = (sm[4] + sm[5]) + (sm[6] + sm[7]);
  }
}

extern "C" void kernel_launch(void* const* d_in, const int* in_sizes, int n_in,
                              void* d_out, int out_size, void* d_ws, size_t ws_size,
                              hipStream_t stream) {
  const float* lstm = (const float*)d_in[0];
  const float* trans = (const float*)d_in[1];
  const int* lens = (const int*)d_in[2];
  const int* tags = (const int*)d_in[3];
  float* ws = (float*)d_ws;
  float* out = (float*)d_out;

  crf_fwd<<<dim3(BB), dim3(64), 0, stream>>>(lstm, trans, lens, tags, ws);
  crf_reduce<<<dim3(1), dim3(256), 0, stream>>>(ws, out);
}

// Round 3
// 210.347 us; speedup vs baseline: 1.5406x; 1.2187x over previous
//
#include <hip/hip_runtime.h>

#define BB 256
#define TT 1024
#define LL 50
#define START_I 47
#define END_I 48

__device__ __forceinline__ float rdlane(float v, int i) {
  return __int_as_float(__builtin_amdgcn_readlane(__float_as_int(v), i));
}

// One wave per sequence. Forward recurrence in scaled-linear domain:
//   q[j] = exp(alpha[j] - 64*ln2*cnt),  q_new[j] = (sum_i q[i]*E[i][j]) * exp(emit[j])
// E[i][j] = exp(trans[i][j]) held in 50 VGPRs (column j in lane j).
// amdgpu_waves_per_eu(1,1): we run exactly 1 wave/CU anyway; open the full
// VGPR file so e[50]+ebuf[8] stay in registers (launch_bounds(64,1) did not).
__global__ __launch_bounds__(64) __attribute__((amdgpu_waves_per_eu(1, 1)))
void crf_fwd(
    const float* __restrict__ lstm, const float* __restrict__ trans,
    const int* __restrict__ lens, const int* __restrict__ tags,
    float* __restrict__ ws) {
  const int b = blockIdx.x;
  const int lane = threadIdx.x;
  const bool act = lane < LL;
  const int cl = act ? lane : (LL - 1);  // clamped column (49 = PAD, finite)
  const int len = lens[b];

  // ---- load E column (lane j holds E[0..49][j]); 0 for dead lanes ----
  float e[LL];
#pragma unroll
  for (int i = 0; i < LL; ++i) {
    float ev = __expf(trans[i * LL + cl]);
    e[i] = act ? ev : 0.0f;
  }

  const float* __restrict__ base = lstm + (size_t)b * TT * LL + cl;

  // ---- alpha0 -> q (dead lanes: q = 0) ----
  float q = act ? __expf(trans[START_I * LL + lane] + base[0]) : 0.0f;
  int cnt = 0;  // alpha = 64*ln2*cnt + ln(q)

  // ---- one recurrence step (branchless rescale) ----
  auto STEP = [&](float em) {
    float acc0 = 0.f, acc1 = 0.f, acc2 = 0.f, acc3 = 0.f;
#pragma unroll
    for (int i = 0; i < 48; i += 4) {
      acc0 = fmaf(rdlane(q, i + 0), e[i + 0], acc0);
      acc1 = fmaf(rdlane(q, i + 1), e[i + 1], acc1);
      acc2 = fmaf(rdlane(q, i + 2), e[i + 2], acc2);
      acc3 = fmaf(rdlane(q, i + 3), e[i + 3], acc3);
    }
    acc0 = fmaf(rdlane(q, 48), e[48], acc0);
    acc1 = fmaf(rdlane(q, 49), e[49], acc1);
    float qn = ((acc0 + acc1) + (acc2 + acc3)) * __expf(em);
    // wave-uniform branchless rescale; dead lanes (qn==0) vote false in both
    unsigned long long up = __ballot(qn >= 0x1p64f);
    unsigned long long dn = __ballot(qn >= 0x1p-64f);
    float s = up ? 0x1p-64f : (dn ? 1.0f : 0x1p64f);
    cnt += up ? 1 : (dn ? 0 : -1);
    q = qn * s;
  };

  // ---- prefetch ring, 8 deep, constant-immediate-offset loads ----
  float ebuf[8];
  const float* p = base + LL;  // t = 1
#pragma unroll
  for (int k = 0; k < 8; ++k) ebuf[k] = p[k * LL];  // t=1..8, always in-row

  const int nb = (len - 1) >> 3;
  const int rem = (len - 1) & 7;

  for (int blk = 0; blk < nb; ++blk) {
    const float* pf = p + 8 * LL;  // refill source: t = 9 + 8*blk + u
    if (blk < 126) {               // 9+8*125+7 = 1023 <= TT-1: always in-row
#pragma unroll
      for (int u = 0; u < 8; ++u) {
        STEP(ebuf[u]);
        ebuf[u] = pf[u * LL];
      }
    } else {                       // last <=2 blocks: guard row overrun
#pragma unroll
      for (int u = 0; u < 8; ++u) {
        STEP(ebuf[u]);
        int tn = 9 + 8 * blk + u;
        if (tn < TT) ebuf[u] = pf[u * LL];
      }
    }
    p = pf;
  }
  for (int u = 0; u < rem; ++u) STEP(ebuf[u]);

  // ---- unlabeled_b = 64*ln2*cnt + ln( sum_j q[j]*exp(trans[j][END]) ) ----
  float w = 0.0f;
  if (act) w = q * __expf(trans[lane * LL + END_I]);
#pragma unroll
  for (int off = 32; off > 0; off >>= 1) w += __shfl_xor(w, off, 64);
  float unl = (float)cnt * 44.361419555836498f + __logf(w);

  // ---- labeled path (gathers over t in lane-strides of 64) ----
  const int* tg = tags + (size_t)b * TT;
  float lab = 0.0f;
  for (int t0 = 0; t0 < len; t0 += 64) {
    int t = t0 + lane;
    if (t >= 1 && t < len) {
      int tp = tg[t - 1];
      int tc = tg[t];
      lab += trans[tp * LL + tc] + lstm[((size_t)b * TT + t) * LL + tc];
    }
  }
#pragma unroll
  for (int off = 32; off > 0; off >>= 1) lab += __shfl_xor(lab, off, 64);

  if (lane == 0) {
    int tg0 = tg[0];
    float begin = trans[START_I * LL + tg0] + lstm[(size_t)b * TT * LL + tg0];
    int tgl = tg[len - 1];
    float endv = trans[tgl * LL + END_I];
    ws[b] = unl;
    ws[BB + b] = lab + begin + endv;
  }
}

// Deterministic final reduce: ws[0..255] -> out[0], ws[256..511] -> out[1]
__global__ __launch_bounds__(256) void crf_reduce(const float* __restrict__ ws,
                                                  float* __restrict__ out) {
  __shared__ float sm[8];
  int tid = threadIdx.x;
  float u = ws[tid];
  float l = ws[BB + tid];
#pragma unroll
  for (int off = 32; off > 0; off >>= 1) {
    u += __shfl_xor(u, off, 64);
    l += __shfl_xor(l, off, 64);
  }
  int wid = tid >> 6;
  if ((tid & 63) == 0) { sm[wid] = u; sm[4 + wid] = l; }
  __syncthreads();
  if (tid == 0) {
    out[0] = (sm[0] + sm[1]) + (sm[2] + sm[3]);
    out[1] = (sm[4] + sm[5]) + (sm[6] + sm[7]);
  }
}

extern "C" void kernel_launch(void* const* d_in, const int* in_sizes, int n_in,
                              void* d_out, int out_size, void* d_ws, size_t ws_size,
                              hipStream_t stream) {
  const float* lstm = (const float*)d_in[0];
  const float* trans = (const float*)d_in[1];
  const int* lens = (const int*)d_in[2];
  const int* tags = (const int*)d_in[3];
  float* ws = (float*)d_ws;
  float* out = (float*)d_out;

  crf_fwd<<<dim3(BB), dim3(64), 0, stream>>>(lstm, trans, lens, tags, ws);
  crf_reduce<<<dim3(1), dim3(256), 0, stream>>>(ws, out);
}